// Round 4
// baseline (2830.434 us; speedup 1.0000x reference)
//
#include <hip/hip_runtime.h>
#include <stdint.h>

// LWTA MLP, decision/value-split architecture:
//   K1a: dense fp32 GEMM -> winner idx + uncertainty flag (gap<=EPS1, clip-aware)
//   K1b: fp64 winner-value recompute (1 col per 16-block = 1/16 FLOPs)
//   K1c: fp64 np-exact resolve of flagged L1 blocks (ballot wave-cooperative)
//   K2a: sparse fp32 GEMM (1-of-16 A) -> winner idx/value + flags
//   K2b: fp64 resolve of flagged L2 blocks (uses fp64 h1 values)
//   K3 : sparse fp32 GEMM -> dense output
// Rationale: np ref is fp64; a single LWTA flip costs ~6e-3 > threshold 4.28e-3.
// fp32 worst-case pre-act error: L1 <= 1.2e-4 (K=1024), L2 <= 8e-6 (256 terms)
// => EPS1=3e-4, EPS2=5e-5 give certain decisions outside flags; flags ~0.1%.

#define EPS1 3.0e-4f
#define EPS2 5.0e-5f

// ---------------------------------------------------------------------------
// K1a: dense fp32 GEMM, 128x256 tile, BK=32, 256 thr, acc 8x(4x4)
#define BM1 128
#define BN1 256
#define ASTR1 (BM1 + 4)
#define BSTR1 (BN1 + 4)

__global__ __launch_bounds__(256)
void k1a_dense_f32_flags(const float* __restrict__ A, const float* __restrict__ Bw,
                         const float* __restrict__ bias, int M, int N, int K,
                         uint8_t* __restrict__ iOut, uint8_t* __restrict__ fOut)
{
    __shared__ float As[32 * ASTR1];
    __shared__ float Bs[32 * BSTR1];
    const int t = threadIdx.x, tx = t & 15, ty = t >> 4;
    const long m0 = (long)blockIdx.y * BM1, n0 = (long)blockIdx.x * BN1;

    float acc[8][4][4];
#pragma unroll
    for (int r = 0; r < 8; ++r)
#pragma unroll
        for (int g = 0; g < 4; ++g)
#pragma unroll
            for (int d = 0; d < 4; ++d) acc[r][g][d] = 0.f;

    for (int k0 = 0; k0 < K; k0 += 32) {
        __syncthreads();
        // B tile: 256 cols x 8 quads = 2048 float4 slots -> 8 iters
#pragma unroll
        for (int i = 0; i < 8; ++i) {
            const int f = i * 256 + t, col = f >> 3, kq = (f & 7) * 4;
            const float4 w = *(const float4*)&Bw[(n0 + col) * (long)K + k0 + kq];
            Bs[(kq + 0) * BSTR1 + col] = w.x;
            Bs[(kq + 1) * BSTR1 + col] = w.y;
            Bs[(kq + 2) * BSTR1 + col] = w.z;
            Bs[(kq + 3) * BSTR1 + col] = w.w;
        }
        // A tile: 128 rows x 8 quads = 1024 slots -> 4 iters
#pragma unroll
        for (int i = 0; i < 4; ++i) {
            const int f = i * 256 + t, row = f >> 3, kq = (f & 7) * 4;
            const float4 a = *(const float4*)&A[(m0 + row) * (long)K + k0 + kq];
            As[(kq + 0) * ASTR1 + row] = a.x;
            As[(kq + 1) * ASTR1 + row] = a.y;
            As[(kq + 2) * ASTR1 + row] = a.z;
            As[(kq + 3) * ASTR1 + row] = a.w;
        }
        __syncthreads();
#pragma unroll
        for (int kk = 0; kk < 32; ++kk) {
            const float4 a0 = *(const float4*)&As[kk * ASTR1 + ty * 8];
            const float4 a1 = *(const float4*)&As[kk * ASTR1 + ty * 8 + 4];
            float4 bb[4];
#pragma unroll
            for (int g = 0; g < 4; ++g)
                bb[g] = *(const float4*)&Bs[kk * BSTR1 + g * 64 + tx * 4];
            const float ar[8] = {a0.x, a0.y, a0.z, a0.w, a1.x, a1.y, a1.z, a1.w};
#pragma unroll
            for (int r = 0; r < 8; ++r)
#pragma unroll
                for (int g = 0; g < 4; ++g) {
                    acc[r][g][0] += ar[r] * bb[g].x;
                    acc[r][g][1] += ar[r] * bb[g].y;
                    acc[r][g][2] += ar[r] * bb[g].z;
                    acc[r][g][3] += ar[r] * bb[g].w;
                }
        }
    }

    const int nb = N >> 4;
#pragma unroll
    for (int r = 0; r < 8; ++r) {
        const long row = m0 + ty * 8 + r;
#pragma unroll
        for (int g = 0; g < 4; ++g) {
            float v1 = -3.f, v2 = -3.f; int i1 = 0, bHi = 0;
#pragma unroll
            for (int d = 0; d < 4; ++d) {
                const long j = n0 + g * 64 + tx * 4 + d;
                const float pre = acc[r][g][d] + bias[j];
                const float c = fminf(fmaxf(pre, -1.f), 1.f);
                const int li = (tx & 3) * 4 + d;
                if (c > v1) { v2 = v1; v1 = c; i1 = li; }
                else if (c > v2) v2 = c;
                bHi |= (pre > 1.f - EPS1 && pre < 1.f + EPS1) ? 1 : 0;
            }
#pragma unroll
            for (int mk = 1; mk <= 2; mk <<= 1) {
                const float ov1 = __shfl_xor(v1, mk);
                const int   oi1 = __shfl_xor(i1, mk);
                const float ov2 = __shfl_xor(v2, mk);
                bHi |= __shfl_xor(bHi, mk);
                if (ov1 > v1 || (ov1 == v1 && oi1 < i1)) {
                    v2 = fmaxf(v1, ov2); v1 = ov1; i1 = oi1;
                } else v2 = fmaxf(v2, ov1);
            }
            if ((tx & 3) == 0) {
                const bool stable = (v1 >= 1.f) && (v2 >= 1.f) && !bHi;
                const int unc = ((v1 - v2 <= EPS1) && !stable) || (v1 <= -1.f + EPS1);
                const long sidx = row * nb + (n0 >> 4) + g * 4 + (tx >> 2);
                iOut[sidx] = (uint8_t)i1;
                fOut[sidx] = (uint8_t)unc;
            }
        }
    }
}

// ---------------------------------------------------------------------------
// K1b: fp64 winner-value recompute. 128x128 tile; thread owns slot w=t&7 of
// rows (t>>3)+{0,32,64,96}. LDS in [row][kq] float4 layout, XOR-swizzled.
__global__ __launch_bounds__(256)
void k1b_winner_f64(const float* __restrict__ A, const float* __restrict__ Bw,
                    const float* __restrict__ bias, int K,
                    const uint8_t* __restrict__ iIn,
                    double* __restrict__ vOutD, float* __restrict__ vOutF)
{
    __shared__ float4 As2[128 * 9];
    __shared__ float4 Bs2[128 * 9];
    const int t = threadIdx.x, w = t & 7, r0 = t >> 3;
    const long m0 = (long)blockIdx.y * 128, n0 = (long)blockIdx.x * 128;

    long cidx[4]; int wj[4]; double acc[4] = {0.0, 0.0, 0.0, 0.0};
#pragma unroll
    for (int q = 0; q < 4; ++q) {
        const int row = r0 + 32 * q;
        cidx[q] = (m0 + row) * 256 + blockIdx.x * 8 + w;
        wj[q] = w * 16 + (int)iIn[cidx[q]];
    }
    for (int k0 = 0; k0 < K; k0 += 32) {
        __syncthreads();
#pragma unroll
        for (int i = 0; i < 4; ++i) {
            const int f = i * 256 + t, rc = f >> 3, kq = f & 7;
            As2[rc * 9 + (kq ^ (rc & 7))] = *(const float4*)&A[(m0 + rc) * (long)K + k0 + kq * 4];
            Bs2[rc * 9 + (kq ^ (rc & 7))] = *(const float4*)&Bw[(n0 + rc) * (long)K + k0 + kq * 4];
        }
        __syncthreads();
#pragma unroll
        for (int q = 0; q < 4; ++q) {
            const int ra = (r0 + 32 * q) * 9, sa = (r0 + 32 * q) & 7;
            const int rb = wj[q] * 9, sb = wj[q] & 7;
            double s = acc[q];
#pragma unroll
            for (int kq = 0; kq < 8; ++kq) {
                const float4 xa = As2[ra + (kq ^ sa)];
                const float4 wb = Bs2[rb + (kq ^ sb)];
                s += (double)xa.x * wb.x + (double)xa.y * wb.y
                   + (double)xa.z * wb.z + (double)xa.w * wb.w;
            }
            acc[q] = s;
        }
    }
#pragma unroll
    for (int q = 0; q < 4; ++q) {
        double v = acc[q] + (double)bias[n0 + wj[q]];
        v = fmin(fmax(v, -1.0), 1.0);
        vOutD[cidx[q]] = v;
        vOutF[cidx[q]] = (float)v;
    }
}

// ---------------------------------------------------------------------------
// K1c: fp64 resolve of flagged L1 blocks. One wave per flagged slot (ballot).
__global__ __launch_bounds__(256)
void k1_resolve(const float* __restrict__ A, const float* __restrict__ Bw,
                const float* __restrict__ bias, const uint8_t* __restrict__ fIn,
                uint8_t* __restrict__ iFix, double* __restrict__ vOutD,
                float* __restrict__ vOutF)
{
    const int gtid = blockIdx.x * 256 + threadIdx.x;
    const int wid = gtid >> 6, lane = gtid & 63;
    const long per = (8192L * 256) / ((gridDim.x * 256) >> 6);
    const long s0 = (long)wid * per;
    for (long c = 0; c < per; c += 64) {
        unsigned long long mask = __ballot(fIn[s0 + c + lane] != 0);
        while (mask) {
            const int bit = __builtin_ctzll(mask); mask &= mask - 1;
            const long s = s0 + c + bit;
            const long row = s >> 8; const int gblk = (int)(s & 255);
            const float4* xp = (const float4*)&A[row * 1024 + lane * 16];
            const float4 x0 = xp[0], x1 = xp[1], x2 = xp[2], x3 = xp[3];
            double best = -3.0; int bi = 0;
            for (int u = 0; u < 16; ++u) {
                const float4* wp = (const float4*)&Bw[(long)(gblk * 16 + u) * 1024 + lane * 16];
                const float4 w0 = wp[0], w1 = wp[1], w2 = wp[2], w3 = wp[3];
                double su = (double)x0.x * w0.x + (double)x0.y * w0.y
                          + (double)x0.z * w0.z + (double)x0.w * w0.w
                          + (double)x1.x * w1.x + (double)x1.y * w1.y
                          + (double)x1.z * w1.z + (double)x1.w * w1.w
                          + (double)x2.x * w2.x + (double)x2.y * w2.y
                          + (double)x2.z * w2.z + (double)x2.w * w2.w
                          + (double)x3.x * w3.x + (double)x3.y * w3.y
                          + (double)x3.z * w3.z + (double)x3.w * w3.w;
#pragma unroll
                for (int off = 32; off; off >>= 1) su += __shfl_xor(su, off);
                const double xu = fmin(fmax(su + (double)bias[gblk * 16 + u], -1.0), 1.0);
                if (xu > best) { best = xu; bi = u; }
            }
            if (lane == 0) { iFix[s] = (uint8_t)bi; vOutD[s] = best; vOutF[s] = (float)best; }
        }
    }
}

// ---------------------------------------------------------------------------
// K2a: sparse fp32 GEMM (1-of-16 A) + LWTA flag epilogue. 128x128, BK=32.
#define BSTR2 132

__global__ __launch_bounds__(256)
void k2a_sparse_f32_flags(const float* __restrict__ vA, const uint8_t* __restrict__ iA,
                          const float* __restrict__ Bw, const float* __restrict__ bias,
                          int M, int N, int K,
                          float* __restrict__ vOut, uint8_t* __restrict__ iOut,
                          uint8_t* __restrict__ fOut)
{
    __shared__ float Bs[32 * BSTR2];
    __shared__ float Av[2 * 128];
    __shared__ int   Ai[2 * 128];
    const int t = threadIdx.x, tx = t & 15, ty = t >> 4;
    const long m0 = (long)blockIdx.y * 128, n0 = (long)blockIdx.x * 128;
    const int nbK = K >> 4;

    float acc[8][2][4];
#pragma unroll
    for (int r = 0; r < 8; ++r)
#pragma unroll
        for (int g = 0; g < 2; ++g)
#pragma unroll
            for (int d = 0; d < 4; ++d) acc[r][g][d] = 0.f;

    for (int k0 = 0; k0 < K; k0 += 32) {
        __syncthreads();
#pragma unroll
        for (int i = 0; i < 4; ++i) {
            const int f = i * 256 + t, col = f >> 3, kq = (f & 7) * 4;
            const float4 w = *(const float4*)&Bw[(n0 + col) * (long)K + k0 + kq];
            Bs[(kq + 0) * BSTR2 + col] = w.x;
            Bs[(kq + 1) * BSTR2 + col] = w.y;
            Bs[(kq + 2) * BSTR2 + col] = w.z;
            Bs[(kq + 3) * BSTR2 + col] = w.w;
        }
        {
            const int row = t & 127, half = t >> 7;
            const long ci = (m0 + row) * (long)nbK + (k0 >> 4) + half;
            Av[half * 128 + row] = vA[ci];
            Ai[half * 128 + row] = (int)iA[ci];
        }
        __syncthreads();
#pragma unroll
        for (int r = 0; r < 8; ++r) {
            const int row = ty * 8 + r;
#pragma unroll
            for (int kb = 0; kb < 2; ++kb) {
                const float v = Av[kb * 128 + row];
                const int  kw = kb * 16 + Ai[kb * 128 + row];
                const float4 b0 = *(const float4*)&Bs[kw * BSTR2 + tx * 4];
                const float4 b1 = *(const float4*)&Bs[kw * BSTR2 + 64 + tx * 4];
                acc[r][0][0] += v * b0.x; acc[r][0][1] += v * b0.y;
                acc[r][0][2] += v * b0.z; acc[r][0][3] += v * b0.w;
                acc[r][1][0] += v * b1.x; acc[r][1][1] += v * b1.y;
                acc[r][1][2] += v * b1.z; acc[r][1][3] += v * b1.w;
            }
        }
    }

    const int nb = N >> 4;
#pragma unroll
    for (int r = 0; r < 8; ++r) {
        const long row = m0 + ty * 8 + r;
#pragma unroll
        for (int g = 0; g < 2; ++g) {
            float v1 = -3.f, v2 = -3.f; int i1 = 0, bHi = 0;
#pragma unroll
            for (int d = 0; d < 4; ++d) {
                const long j = n0 + g * 64 + tx * 4 + d;
                const float pre = acc[r][g][d] + bias[j];
                const float cv = fminf(fmaxf(pre, -1.f), 1.f);
                const int li = (tx & 3) * 4 + d;
                if (cv > v1) { v2 = v1; v1 = cv; i1 = li; }
                else if (cv > v2) v2 = cv;
                bHi |= (pre > 1.f - EPS2 && pre < 1.f + EPS2) ? 1 : 0;
            }
#pragma unroll
            for (int mk = 1; mk <= 2; mk <<= 1) {
                const float ov1 = __shfl_xor(v1, mk);
                const int   oi1 = __shfl_xor(i1, mk);
                const float ov2 = __shfl_xor(v2, mk);
                bHi |= __shfl_xor(bHi, mk);
                if (ov1 > v1 || (ov1 == v1 && oi1 < i1)) {
                    v2 = fmaxf(v1, ov2); v1 = ov1; i1 = oi1;
                } else v2 = fmaxf(v2, ov1);
            }
            if ((tx & 3) == 0) {
                const bool stable = (v1 >= 1.f) && (v2 >= 1.f) && !bHi;
                const int unc = ((v1 - v2 <= EPS2) && !stable) || (v1 <= -1.f + EPS2);
                const long sidx = row * nb + (n0 >> 4) + g * 4 + (tx >> 2);
                vOut[sidx] = v1;
                iOut[sidx] = (uint8_t)i1;
                fOut[sidx] = (uint8_t)unc;
            }
        }
    }
}

// ---------------------------------------------------------------------------
// K2b: fp64 resolve of flagged L2 blocks using fp64 h1 values.
__global__ __launch_bounds__(256)
void k2_resolve(const double* __restrict__ vA, const uint8_t* __restrict__ iA,
                const float* __restrict__ W2r, const float* __restrict__ bias,
                const uint8_t* __restrict__ fIn, uint8_t* __restrict__ iFix,
                float* __restrict__ vFix)
{
    const int gtid = blockIdx.x * 256 + threadIdx.x;
    const int wid = gtid >> 6, lane = gtid & 63;
    const long per = (8192L * 256) / ((gridDim.x * 256) >> 6);
    const long s0 = (long)wid * per;
    for (long c = 0; c < per; c += 64) {
        unsigned long long mask = __ballot(fIn[s0 + c + lane] != 0);
        while (mask) {
            const int bit = __builtin_ctzll(mask); mask &= mask - 1;
            const long s = s0 + c + bit;
            const long row = s >> 8; const int gblk = (int)(s & 255);
            double hv[4]; int kp[4];
#pragma unroll
            for (int q = 0; q < 4; ++q) {
                const int b = lane * 4 + q;
                const long ci = row * 256 + b;
                hv[q] = vA[ci];
                kp[q] = b * 16 + (int)iA[ci];
            }
            double best = -3.0; int bi = 0;
            for (int u = 0; u < 16; ++u) {
                const float* wr = &W2r[(long)(gblk * 16 + u) * 4096];
                double su = hv[0] * (double)wr[kp[0]] + hv[1] * (double)wr[kp[1]]
                          + hv[2] * (double)wr[kp[2]] + hv[3] * (double)wr[kp[3]];
#pragma unroll
                for (int off = 32; off; off >>= 1) su += __shfl_xor(su, off);
                const double xu = fmin(fmax(su + (double)bias[gblk * 16 + u], -1.0), 1.0);
                if (xu > best) { best = xu; bi = u; }
            }
            if (lane == 0) { iFix[s] = (uint8_t)bi; vFix[s] = (float)best; }
        }
    }
}

// ---------------------------------------------------------------------------
// K3: sparse fp32 GEMM -> dense output (unchanged round-3 structure)
__global__ __launch_bounds__(256)
void k3_sparse_f32_out(const float* __restrict__ vA, const uint8_t* __restrict__ iA,
                       const float* __restrict__ Bw, const float* __restrict__ bias,
                       int M, int N, int K, float* __restrict__ dOut)
{
    __shared__ float Bs[32 * BSTR2];
    __shared__ float Av[2 * 128];
    __shared__ int   Ai[2 * 128];
    const int t = threadIdx.x, tx = t & 15, ty = t >> 4;
    const long m0 = (long)blockIdx.y * 128, n0 = (long)blockIdx.x * 128;
    const int nbK = K >> 4;

    float acc[8][2][4];
#pragma unroll
    for (int r = 0; r < 8; ++r)
#pragma unroll
        for (int g = 0; g < 2; ++g)
#pragma unroll
            for (int d = 0; d < 4; ++d) acc[r][g][d] = 0.f;

    for (int k0 = 0; k0 < K; k0 += 32) {
        __syncthreads();
#pragma unroll
        for (int i = 0; i < 4; ++i) {
            const int f = i * 256 + t, col = f >> 3, kq = (f & 7) * 4;
            const float4 w = *(const float4*)&Bw[(n0 + col) * (long)K + k0 + kq];
            Bs[(kq + 0) * BSTR2 + col] = w.x;
            Bs[(kq + 1) * BSTR2 + col] = w.y;
            Bs[(kq + 2) * BSTR2 + col] = w.z;
            Bs[(kq + 3) * BSTR2 + col] = w.w;
        }
        {
            const int row = t & 127, half = t >> 7;
            const long ci = (m0 + row) * (long)nbK + (k0 >> 4) + half;
            Av[half * 128 + row] = vA[ci];
            Ai[half * 128 + row] = (int)iA[ci];
        }
        __syncthreads();
#pragma unroll
        for (int r = 0; r < 8; ++r) {
            const int row = ty * 8 + r;
#pragma unroll
            for (int kb = 0; kb < 2; ++kb) {
                const float v = Av[kb * 128 + row];
                const int  kw = kb * 16 + Ai[kb * 128 + row];
                const float4 b0 = *(const float4*)&Bs[kw * BSTR2 + tx * 4];
                const float4 b1 = *(const float4*)&Bs[kw * BSTR2 + 64 + tx * 4];
                acc[r][0][0] += v * b0.x; acc[r][0][1] += v * b0.y;
                acc[r][0][2] += v * b0.z; acc[r][0][3] += v * b0.w;
                acc[r][1][0] += v * b1.x; acc[r][1][1] += v * b1.y;
                acc[r][1][2] += v * b1.z; acc[r][1][3] += v * b1.w;
            }
        }
    }
#pragma unroll
    for (int r = 0; r < 8; ++r) {
        const long row = m0 + ty * 8 + r;
#pragma unroll
        for (int g = 0; g < 2; ++g) {
            const long j = n0 + g * 64 + tx * 4;
            float4 o;
            o.x = acc[r][g][0] + bias[j + 0];
            o.y = acc[r][g][1] + bias[j + 1];
            o.z = acc[r][g][2] + bias[j + 2];
            o.w = acc[r][g][3] + bias[j + 3];
            *(float4*)&dOut[row * (long)N + j] = o;
        }
    }
}

// ---------------------------------------------------------------------------
extern "C" void kernel_launch(void* const* d_in, const int* in_sizes, int n_in,
                              void* d_out, int out_size, void* d_ws, size_t ws_size,
                              hipStream_t stream)
{
    const float* x    = (const float*)d_in[0];
    const float* W1   = (const float*)d_in[1];
    const float* b1   = (const float*)d_in[2];
    const float* W2   = (const float*)d_in[3];
    const float* b2   = (const float*)d_in[4];
    const float* Wout = (const float*)d_in[5];
    const float* bout = (const float*)d_in[6];
    float* out = (float*)d_out;
    (void)in_sizes; (void)n_in; (void)out_size; (void)ws_size;

    const int B = 8192, Din = 1024, H = 4096, Dout = 1024;

    char* ws = (char*)d_ws;
    double*  v1d = (double*)ws;                       // 16 MB
    float*   v1f = (float*)(ws + (16ll << 20));       //  8 MB
    uint8_t* i1  = (uint8_t*)(ws + (24ll << 20));     //  2 MB
    uint8_t* f1  = (uint8_t*)(ws + (26ll << 20));     //  2 MB
    float*   v2f = (float*)(ws + (28ll << 20));       //  8 MB
    uint8_t* i2  = (uint8_t*)(ws + (36ll << 20));     //  2 MB
    uint8_t* f2  = (uint8_t*)(ws + (38ll << 20));     //  2 MB

    dim3 blk(256);
    k1a_dense_f32_flags<<<dim3(H / BN1, B / BM1), blk, 0, stream>>>(
        x, W1, b1, B, H, Din, i1, f1);
    k1b_winner_f64<<<dim3(H / 128, B / 128), blk, 0, stream>>>(
        x, W1, b1, Din, i1, v1d, v1f);
    k1_resolve<<<1024, blk, 0, stream>>>(x, W1, b1, f1, i1, v1d, v1f);
    k2a_sparse_f32_flags<<<dim3(H / 128, B / 128), blk, 0, stream>>>(
        v1f, i1, W2, b2, B, H, H, v2f, i2, f2);
    k2_resolve<<<1024, blk, 0, stream>>>(v1d, i1, W2, b2, f2, i2, v2f);
    k3_sparse_f32_out<<<dim3(Dout / 128, B / 128), blk, 0, stream>>>(
        v2f, i2, Wout, bout, B, Dout, H, out);
}